// Round 8
// baseline (182.169 us; speedup 1.0000x reference)
//
#include <hip/hip_runtime.h>
#include <hip/hip_bf16.h>

// NPZD plankton ODE: B*WK = 106496 independent trajectories, 56 Euler steps.
//
// R8: R7 counters showed VALUBusy 40% + 557k LDS conflicts -- the every-3rd
// compaction (cndmask element selects, magic divs, scattered b32 writes) was
// the cost, plus partially-serialized staging (VGPR=48). Fix:
//  - Stage RAW half-rows into LDS via global_load_lds width-16 DMA (pure
//    contiguous copy = exactly the DMA contract; compiler cannot serialize
//    it -- R4-proven; no staged VGPRs, no compaction at all).
//  - Integrate directly from raw LDS: sample s=4g+c of week wl lives at word
//    168*wl + 12*g + {0,3,6,9} -> 3x ds_read_b128 per 4 steps, static
//    component picks {r0.x, r0.w, r1.z, r2.y} (free register selection).
//    b128 runs in 16-lane phases -> only ~4-way bank aliasing (~1.6x).
// LDS 36.9 KB -> 4 blocks/CU. One barrier. Floor ~24 us (fill-calibrated
// 6.6 TB/s on 157 MB).

typedef float f32x4 __attribute__((ext_vector_type(4)));

#define NPZD_B 2048
#define NPZD_WK 52
#define NPZD_HRS 8760
#define NPZD_HWK 26              // weeks per block (half batch)
#define NPZD_NF4H 1092           // f4 per half-row week-range (4368 words)
#define NPZD_NF4 2190            // f4 per full row (8760 words)
#define NPZD_LDSW 4608           // words per array: 18 DMA iters * 256

__global__ __launch_bounds__(256) void npzd_kernel(
    const float* __restrict__ X_in,     // (B, WK, 5, 1)
    const float* __restrict__ gf,       // (B, HRS)
    const float* __restrict__ gm,       // (B, HRS)
    const float* __restrict__ params,   // (B, 10)
    const float* __restrict__ dt_ptr,   // scalar
    float* __restrict__ out)            // (B, WK, 4, 8)
{
    __shared__ __align__(16) float lds_f[NPZD_LDSW];
    __shared__ __align__(16) float lds_m[NPZD_LDSW];

    const int blk  = blockIdx.x;
    const int b    = blk >> 1;          // batch
    const int q    = blk & 1;           // half: weeks [26q, 26q+26)
    const int tid  = threadIdx.x;
    const int wid  = tid >> 6;
    const int lane = tid & 63;

    const f32x4* __restrict__ gf4 = (const f32x4*)(gf + (size_t)b * NPZD_HRS);
    const f32x4* __restrict__ gm4 = (const f32x4*)(gm + (size_t)b * NPZD_HRS);

    // ---- Phase 1: DMA the half-row (f and m) into LDS, raw ----
    // iter it copies f4 [it*64, it*64+64) of this half; 18 iters covers
    // 1152 f4 (>=1092; overrun lands in the unread pad region). Source
    // clamped to the row's last f4 (2189) -- always in-bounds.
    const int k0 = q * NPZD_NF4H;
    #pragma unroll
    for (int j = 0; j < 5; ++j) {
        const int it = j * 4 + wid;
        if (it < 18) {                       // wave-uniform branch (j==4 only)
            int k = k0 + it * 64 + lane;
            k = (k > NPZD_NF4 - 1) ? (NPZD_NF4 - 1) : k;
            __builtin_amdgcn_global_load_lds(
                (const __attribute__((address_space(1))) void*)(gf4 + k),
                (__attribute__((address_space(3))) void*)(lds_f + it * 256), 16, 0, 0);
            __builtin_amdgcn_global_load_lds(
                (const __attribute__((address_space(1))) void*)(gm4 + k),
                (__attribute__((address_space(3))) void*)(lds_m + it * 256), 16, 0, 0);
        }
    }
    __syncthreads();   // single vmcnt drain

    // ---- Phase 2: lanes 0..25 integrate one trajectory each ----
    if (tid >= NPZD_HWK) return;
    const int wl = tid;                 // local week
    const int w  = q * NPZD_HWK + wl;   // global week

    const float dt = dt_ptr[0];         // 0.125

    const float* xb = X_in + ((size_t)b * NPZD_WK + w) * 5;
    float N = xb[1], P = xb[2], Z = xb[3], D = xb[4];

    const float* pp = params + (size_t)b * 10;   // block-uniform -> s_load
    const float chi   = pp[0];
    const float rho2  = pp[1] * 2.0f;
    const float gam1  = pp[2] * 0.1f;
    const float lam05 = pp[3] * 0.05f;
    const float eps1  = pp[4] * 0.1f;
    const float alp3  = pp[5] * 0.3f;
    const float bet6  = pp[6] * 0.6f;
    const float eta15 = pp[7] * 0.15f;
    const float phi4  = pp[8] * 0.4f;
    const float zet1  = pp[9] * 0.1f;
    const float rem   = 1.0f - alp3 - bet6;

    float oN[8], oP[8], oZ[8], oD[8];
    oN[0] = N; oP[0] = P; oZ[0] = Z; oD[0] = D;

    const float* lf = lds_f + 168 * wl;
    const float* lm = lds_m + 168 * wl;

    #pragma unroll
    for (int g = 0; g < 14; ++g) {
        // samples s=4g+c at words 12g+{0,3,6,9}: read 12 words as 3 b128,
        // pick {r0.x, r0.w, r1.z, r2.y} -- static, no VALU select.
        const f32x4 a0 = *(const f32x4*)(lf + 12 * g);
        const f32x4 a1 = *(const f32x4*)(lf + 12 * g + 4);
        const f32x4 a2 = *(const f32x4*)(lf + 12 * g + 8);
        const f32x4 c0 = *(const f32x4*)(lm + 12 * g);
        const f32x4 c1 = *(const f32x4*)(lm + 12 * g + 4);
        const f32x4 c2 = *(const f32x4*)(lm + 12 * g + 8);
        const float fs[4] = {a0.x, a0.w, a1.z, a2.y};
        const float ms[4] = {c0.x, c0.w, c1.z, c2.y};
        #pragma unroll
        for (int c = 0; c < 4; ++c) {
            const float ft = fs[c], mt = ms[c];
            const float Pc = fmaxf(0.01f, P);
            const float Zc = fmaxf(0.01f, Z);
            const float gN = N * __builtin_amdgcn_rcpf(chi + N);
            const float zg = rho2 * (1.0f - __expf(-lam05 * Pc)) * Zc;
            const float up = gN * ft * Pc;
            const float Nn = N + dt * (-up + alp3 * zg + eps1 * P + gam1 * Z + phi4 * D + mt * (8.0f - N));
            const float Pn = P + dt * (up - zg - eps1 * P - eta15 * P - mt * P);
            const float Zn = Z + dt * (bet6 * zg - gam1 * Z - mt * Z);
            const float Dn = D + dt * (eta15 * P + rem * zg - phi4 * D - zet1 * D - mt * D);
            N = Nn; P = Pn; Z = Zn; D = Dn;
        }
        if (g & 1) {   // after steps 7,15,...,55
            const int cc = (g >> 1) + 1;
            oN[cc] = N; oP[cc] = P; oZ[cc] = Z; oD[cc] = D;
        }
    }

    // Output: (b, w, state, 8) -> 32 contiguous floats per trajectory.
    // R1-R7 measured WRITE_SIZE == output bytes exactly -> no RMW penalty.
    f32x4* o4 = (f32x4*)(out + ((size_t)b * NPZD_WK + w) * 32);
    o4[0] = (f32x4){oN[0], oN[1], oN[2], oN[3]};
    o4[1] = (f32x4){oN[4], oN[5], oN[6], oN[7]};
    o4[2] = (f32x4){oP[0], oP[1], oP[2], oP[3]};
    o4[3] = (f32x4){oP[4], oP[5], oP[6], oP[7]};
    o4[4] = (f32x4){oZ[0], oZ[1], oZ[2], oZ[3]};
    o4[5] = (f32x4){oZ[4], oZ[5], oZ[6], oZ[7]};
    o4[6] = (f32x4){oD[0], oD[1], oD[2], oD[3]};
    o4[7] = (f32x4){oD[4], oD[5], oD[6], oD[7]};
}

extern "C" void kernel_launch(void* const* d_in, const int* in_sizes, int n_in,
                              void* d_out, int out_size, void* d_ws, size_t ws_size,
                              hipStream_t stream) {
    const float* X_in   = (const float*)d_in[0];
    const float* gf     = (const float*)d_in[1];
    const float* gm     = (const float*)d_in[2];
    const float* params = (const float*)d_in[3];
    const float* dt_ptr = (const float*)d_in[4];
    float* out = (float*)d_out;

    npzd_kernel<<<NPZD_B * 2, 256, 0, stream>>>(X_in, gf, gm, params, dt_ptr, out);
}